// Round 3
// baseline (1404.214 us; speedup 1.0000x reference)
//
#include <hip/hip_runtime.h>

// Problem constants
constexpr int D  = 128;
constexpr int M  = 8192;
constexpr int L  = 5;
constexpr int K  = 8;
constexpr int KL = 4;
constexpr int G  = 4096;

constexpr int TR   = 32;            // rows per block tile
constexpr int PADL = M + K * TR;    // 8448 -> 264 tiles
constexpr int PADG = G + KL * TR;   // 4224 -> 132 tiles

typedef short bf16x8 __attribute__((ext_vector_type(8)));
typedef float f32x4  __attribute__((ext_vector_type(4)));

__device__ __forceinline__ unsigned short f2bf(float x) {
  union { float f; unsigned int u; } c; c.f = x;
  unsigned int u = c.u + 0x7FFF + ((c.u >> 16) & 1);   // RNE
  return (unsigned short)(u >> 16);
}
__device__ __forceinline__ float bf2f(unsigned short h) {
  union { unsigned int u; float f; } c; c.u = ((unsigned int)h) << 16;
  return c.f;
}

// ---------------------------------------------------------------------------
__global__ void leaf_gather_kernel(const int* __restrict__ leaf_ids,
                                   const float* __restrict__ emb,
                                   float* __restrict__ h0) {
  int idx = blockIdx.x * 256 + threadIdx.x;
  int n = idx >> 7, d = idx & 127;
  h0[idx] = emb[(size_t)leaf_ids[n] * D + d];
}

// ---------------------------------------------------------------------------
// Bucket node indices by fid, padded to TR boundaries; pad entries = -1.
// Valid entries are a contiguous prefix of each bucket -> each 32-row tile has
// uniform fid and valid rows as a prefix.
__global__ void bucket32_kernel(const int* __restrict__ nf_fid,
                                const int* __restrict__ lf_fid,
                                int* __restrict__ orders) {
  int b = blockIdx.x;
  const int* fid; int N, Kf, cap; int* out;
  if (b < L) { fid = nf_fid + b * M; N = M; Kf = K;  cap = PADL; out = orders + b * PADL; }
  else       { fid = lf_fid;         N = G; Kf = KL; cap = PADG; out = orders + L * PADL; }
  __shared__ int cnt[8];
  __shared__ int cur[8];
  int tid = threadIdx.x;
  if (tid < Kf) cnt[tid] = 0;
  __syncthreads();
  for (int i = tid; i < N; i += 256) atomicAdd(&cnt[fid[i]], 1);
  __syncthreads();
  if (tid == 0) {
    int off = 0;
    for (int k = 0; k < Kf; ++k) { cur[k] = off; off += ((cnt[k] + TR - 1) / TR) * TR; }
  }
  __syncthreads();
  for (int i = tid; i < cap; i += 256) out[i] = -1;
  __syncthreads();
  for (int i = tid; i < N; i += 256) {
    int kk = fid[i];
    int pos = atomicAdd(&cur[kk], 1);
    out[pos] = i;
  }
}

// ---------------------------------------------------------------------------
// Weight prep: W[k][KD][F] fp32 -> BT[k][F][2*KD] bf16 as [hi(KD) | lo(KD)].
__global__ void prep_kernel(const float* __restrict__ W1, const float* __restrict__ W2,
                            const float* __restrict__ W3, const float* __restrict__ Wl1,
                            const float* __restrict__ Wl2,
                            short* __restrict__ B1T, short* __restrict__ B2T,
                            short* __restrict__ B3T, short* __restrict__ BL1T,
                            short* __restrict__ BL2T) {
  int b = blockIdx.x;
  const float* W; short* BT; int KD, F;
  if      (b < 4096) { W = W1;  BT = B1T;  KD = 256; F = 512; }
  else if (b < 6144) { W = W2;  BT = B2T;  KD = 512; F = 256; b -= 4096; }
  else if (b < 7168) { W = W3;  BT = B3T;  KD = 256; F = 128; b -= 6144; }
  else if (b < 9216) { W = Wl1; BT = BL1T; KD = 256; F = 512; b -= 7168; }
  else               { W = Wl2; BT = BL2T; KD = 512; F = 128; b -= 9216; }
  int k = b / F, f = b % F;
  for (int d = threadIdx.x; d < KD; d += 256) {
    float w = W[((size_t)k * KD + d) * F + f];
    unsigned short hi = f2bf(w);
    unsigned short lo = f2bf(w - bf2f(hi));
    BT[((size_t)k * F + f) * (2 * KD) + d]      = (short)hi;
    BT[((size_t)k * F + f) * (2 * KD) + KD + d] = (short)lo;
  }
}

// ---------------------------------------------------------------------------
// Fused level kernel: 32 rows/block (uniform fid), all 3 layers in one kernel.
// Split-bf16 3-segment trick: A' segs {hi,lo,hi}, B' segs {hi,hi,lo}.
// LDS: xs (x / later a2, split) 33.3KB + a1c (a1 chunk, split) 16.9KB +
//      Bst (weight staging) 18.4KB  ~= 69KB -> 2 blocks/CU.
// Waves: 2 (row) x 2 (col); wave tile 16 rows x 64 cols per 128-col chunk.
__global__ __launch_bounds__(256) void level_fused(
    const float* __restrict__ h_in, float* __restrict__ h_out,
    const int* __restrict__ order, const int* __restrict__ fid,
    const int* __restrict__ li, const int* __restrict__ ri,
    const short* __restrict__ B1T, const float* __restrict__ b1,
    const short* __restrict__ B2T, const float* __restrict__ b2,
    const short* __restrict__ B3T, const float* __restrict__ b3) {
  constexpr int XLDA = 520, A1LDA = 264, BLDA = 72;
  __shared__ __align__(16) short xs[32 * XLDA];    // x split [hi256|lo256]; later a2
  __shared__ __align__(16) short a1c[32 * A1LDA];  // a1 chunk split [hi128|lo128]
  __shared__ __align__(16) short Bst[128 * BLDA];  // weight chunk: 128 cols x 64 k
  __shared__ int nodesS[32], liS[32], riS[32];

  const int tid = threadIdx.x;
  if (tid < TR) {
    int node = order[blockIdx.x * TR + tid];
    nodesS[tid] = node;
    liS[tid] = node >= 0 ? li[node] : 0;
    riS[tid] = node >= 0 ? ri[node] : 0;
  }
  __syncthreads();
  if (nodesS[0] < 0) return;                 // fully-padded tile
  const int kfn = fid[nodesS[0]];
  const short* __restrict__ B1k = B1T + (size_t)kfn * 512 * 512;
  const short* __restrict__ B2k = B2T + (size_t)kfn * 256 * 1024;
  const short* __restrict__ B3k = B3T + (size_t)kfn * 128 * 512;

  // gather + split x into xs: thread -> (row, 32-dim slice)
  {
    const int row = tid >> 3;
    const int d0 = (tid & 7) * 32;
    float v[32];
    if (nodesS[row] >= 0) {
      const float* src = (d0 < 128) ? (h_in + (size_t)liS[row] * 128 + d0)
                                    : (h_in + (size_t)riS[row] * 128 + (d0 - 128));
      const float4* p = (const float4*)src;
      #pragma unroll
      for (int i = 0; i < 8; ++i) ((float4*)v)[i] = p[i];
    } else {
      #pragma unroll
      for (int i = 0; i < 32; ++i) v[i] = 0.f;
    }
    union { unsigned short h[32]; int4 q[4]; } hi, lo;
    #pragma unroll
    for (int i = 0; i < 32; ++i) {
      unsigned short hh = f2bf(v[i]);
      hi.h[i] = hh;
      lo.h[i] = f2bf(v[i] - bf2f(hh));
    }
    int4* dh = (int4*)&xs[row * XLDA + d0];
    int4* dl = (int4*)&xs[row * XLDA + 256 + d0];
    #pragma unroll
    for (int i = 0; i < 4; ++i) { dh[i] = hi.q[i]; dl[i] = lo.q[i]; }
  }
  // (layer1 loop's first barrier covers the gather->read hazard)

  const int lane = tid & 63, wave = tid >> 6;
  const int wr = (wave >> 1) * 16;      // wave row base (0/16)
  const int wc = wave & 1;              // wave col group
  const int l15 = lane & 15, oct = lane >> 4;

  const int scol = tid >> 1, shalf = tid & 1;   // staging: 128 cols x 2 halves
  int4 br[4];                                    // prefetch regs (64B)

  f32x4 acc2[8];
  #pragma unroll
  for (int i = 0; i < 8; ++i) acc2[i] = (f32x4)0.f;

  for (int nc = 0; nc < 4; ++nc) {
    f32x4 acc1[4];
    #pragma unroll
    for (int i = 0; i < 4; ++i) acc1[i] = (f32x4)0.f;

    // ---- layer 1: a1 cols nc*128..+128, K' = 3*256 = 768 (12 chunks of 64)
    {
      auto loadB1 = [&](int c) {
        int ko = c * 64, seg = ko >> 8, wi = ko & 255;
        int pb = (seg == 2) ? 256 + wi : wi;
        const int4* p = (const int4*)(B1k + (size_t)(nc * 128 + scol) * 512 + pb + shalf * 32);
        br[0] = p[0]; br[1] = p[1]; br[2] = p[2]; br[3] = p[3];
      };
      loadB1(0);
      for (int c = 0; c < 12; ++c) {
        __syncthreads();
        { int4* d4 = (int4*)&Bst[scol * BLDA + shalf * 32];
          d4[0] = br[0]; d4[1] = br[1]; d4[2] = br[2]; d4[3] = br[3]; }
        __syncthreads();
        if (c + 1 < 12) loadB1(c + 1);
        int ko = c * 64, seg = ko >> 8, wi = ko & 255;
        int pa = (seg == 1) ? 256 + wi : wi;
        #pragma unroll
        for (int s = 0; s < 2; ++s) {
          bf16x8 a = *(const bf16x8*)&xs[(wr + l15) * XLDA + pa + s * 32 + oct * 8];
          #pragma unroll
          for (int cf = 0; cf < 4; ++cf) {
            bf16x8 b = *(const bf16x8*)&Bst[(wc * 64 + cf * 16 + l15) * BLDA + s * 32 + oct * 8];
            acc1[cf] = __builtin_amdgcn_mfma_f32_16x16x32_bf16(a, b, acc1[cf], 0, 0, 0);
          }
        }
      }
    }
    // epilogue 1 -> a1c (a1c last read >=2 barriers ago)
    #pragma unroll
    for (int cf = 0; cf < 4; ++cf) {
      int colL = wc * 64 + cf * 16 + l15;
      float bv = b1[kfn * 512 + nc * 128 + colL];
      #pragma unroll
      for (int j = 0; j < 4; ++j) {
        int row = wr + oct * 4 + j;
        float v = fmaxf(acc1[cf][j] + bv, 0.f);
        unsigned short hh = f2bf(v);
        a1c[row * A1LDA + colL]       = (short)hh;
        a1c[row * A1LDA + 128 + colL] = (short)f2bf(v - bf2f(hh));
      }
    }
    // ---- layer 2 partial: this chunk's logical K = 3*128 = 384; N=256 in 2 halves
    {
      auto loadB2 = [&](int u) {
        int cc = u >> 1, h = u & 1;
        int ko = cc * 64, seg = ko >> 7, wi = ko & 127;
        int pb = (seg == 2) ? 512 + nc * 128 + wi : nc * 128 + wi;
        const int4* p = (const int4*)(B2k + (size_t)(h * 128 + scol) * 1024 + pb + shalf * 32);
        br[0] = p[0]; br[1] = p[1]; br[2] = p[2]; br[3] = p[3];
      };
      loadB2(0);
      for (int u = 0; u < 12; ++u) {        // u = cc*2 + h
        int cc = u >> 1, h = u & 1;
        __syncthreads();
        { int4* d4 = (int4*)&Bst[scol * BLDA + shalf * 32];
          d4[0] = br[0]; d4[1] = br[1]; d4[2] = br[2]; d4[3] = br[3]; }
        __syncthreads();
        if (u + 1 < 12) loadB2(u + 1);
        int ko = cc * 64, seg = ko >> 7, wi = ko & 127;
        int pa = (seg == 1) ? 128 + wi : wi;
        #pragma unroll
        for (int s = 0; s < 2; ++s) {
          bf16x8 a = *(const bf16x8*)&a1c[(wr + l15) * A1LDA + pa + s * 32 + oct * 8];
          #pragma unroll
          for (int cf = 0; cf < 4; ++cf) {
            bf16x8 b = *(const bf16x8*)&Bst[(wc * 64 + cf * 16 + l15) * BLDA + s * 32 + oct * 8];
            acc2[h * 4 + cf] = __builtin_amdgcn_mfma_f32_16x16x32_bf16(a, b, acc2[h * 4 + cf], 0, 0, 0);
          }
        }
      }
    }
  }
  // epilogue 2 -> xs reused as a2 split (all waves past last layer-2 barrier;
  // nobody reads xs again until after layer-3's staging barriers)
  #pragma unroll
  for (int h = 0; h < 2; ++h) {
    #pragma unroll
    for (int cf = 0; cf < 4; ++cf) {
      int col = h * 128 + wc * 64 + cf * 16 + l15;
      float bv = b2[kfn * 256 + col];
      #pragma unroll
      for (int j = 0; j < 4; ++j) {
        int row = wr + oct * 4 + j;
        float v = fmaxf(acc2[h * 4 + cf][j] + bv, 0.f);
        unsigned short hh = f2bf(v);
        xs[row * XLDA + col]       = (short)hh;
        xs[row * XLDA + 256 + col] = (short)f2bf(v - bf2f(hh));
      }
    }
  }
  // ---- layer 3: N=128, K' = 768 over xs(a2)
  f32x4 acc3[4];
  #pragma unroll
  for (int i = 0; i < 4; ++i) acc3[i] = (f32x4)0.f;
  {
    auto loadB3 = [&](int c) {
      int ko = c * 64, seg = ko >> 8, wi = ko & 255;
      int pb = (seg == 2) ? 256 + wi : wi;
      const int4* p = (const int4*)(B3k + (size_t)scol * 512 + pb + shalf * 32);
      br[0] = p[0]; br[1] = p[1]; br[2] = p[2]; br[3] = p[3];
    };
    loadB3(0);
    for (int c = 0; c < 12; ++c) {
      __syncthreads();
      { int4* d4 = (int4*)&Bst[scol * BLDA + shalf * 32];
        d4[0] = br[0]; d4[1] = br[1]; d4[2] = br[2]; d4[3] = br[3]; }
      __syncthreads();
      if (c + 1 < 12) loadB3(c + 1);
      int ko = c * 64, seg = ko >> 8, wi = ko & 255;
      int pa = (seg == 1) ? 256 + wi : wi;
      #pragma unroll
      for (int s = 0; s < 2; ++s) {
        bf16x8 a = *(const bf16x8*)&xs[(wr + l15) * XLDA + pa + s * 32 + oct * 8];
        #pragma unroll
        for (int cf = 0; cf < 4; ++cf) {
          bf16x8 b = *(const bf16x8*)&Bst[(wc * 64 + cf * 16 + l15) * BLDA + s * 32 + oct * 8];
          acc3[cf] = __builtin_amdgcn_mfma_f32_16x16x32_bf16(a, b, acc3[cf], 0, 0, 0);
        }
      }
    }
  }
  // epilogue 3: bias + scatter fp32
  #pragma unroll
  for (int cf = 0; cf < 4; ++cf) {
    int col = wc * 64 + cf * 16 + l15;
    float bv = b3[kfn * 128 + col];
    #pragma unroll
    for (int j = 0; j < 4; ++j) {
      int row = wr + oct * 4 + j;
      int node = nodesS[row];
      if (node >= 0) h_out[(size_t)node * 128 + col] = acc3[cf][j] + bv;
    }
  }
}

// ---------------------------------------------------------------------------
// Fused logic kernel: layer1 (256->512, relu) + layer2 (512->128) per 32 rows.
__global__ __launch_bounds__(256) void logic_fused(
    const float* __restrict__ h, float* __restrict__ out,
    const int* __restrict__ order, const int* __restrict__ fid,
    const int* __restrict__ gl, const int* __restrict__ gr,
    const short* __restrict__ BL1T, const float* __restrict__ bl1,
    const short* __restrict__ BL2T, const float* __restrict__ bl2) {
  constexpr int XLDA = 520, A1LDA = 264, BLDA = 72;
  __shared__ __align__(16) short xs[32 * XLDA];
  __shared__ __align__(16) short a1c[32 * A1LDA];
  __shared__ __align__(16) short Bst[128 * BLDA];
  __shared__ int nodesS[32], liS[32], riS[32];

  const int tid = threadIdx.x;
  if (tid < TR) {
    int node = order[blockIdx.x * TR + tid];
    nodesS[tid] = node;
    liS[tid] = node >= 0 ? gl[node] : 0;
    riS[tid] = node >= 0 ? gr[node] : 0;
  }
  __syncthreads();
  if (nodesS[0] < 0) return;
  const int kfn = fid[nodesS[0]];
  const short* __restrict__ B1k = BL1T + (size_t)kfn * 512 * 512;
  const short* __restrict__ B2k = BL2T + (size_t)kfn * 128 * 1024;

  {
    const int row = tid >> 3;
    const int d0 = (tid & 7) * 32;
    float v[32];
    if (nodesS[row] >= 0) {
      const float* src = (d0 < 128) ? (h + (size_t)liS[row] * 128 + d0)
                                    : (h + (size_t)riS[row] * 128 + (d0 - 128));
      const float4* p = (const float4*)src;
      #pragma unroll
      for (int i = 0; i < 8; ++i) ((float4*)v)[i] = p[i];
    } else {
      #pragma unroll
      for (int i = 0; i < 32; ++i) v[i] = 0.f;
    }
    union { unsigned short h16[32]; int4 q[4]; } hi, lo;
    #pragma unroll
    for (int i = 0; i < 32; ++i) {
      unsigned short hh = f2bf(v[i]);
      hi.h16[i] = hh;
      lo.h16[i] = f2bf(v[i] - bf2f(hh));
    }
    int4* dh = (int4*)&xs[row * XLDA + d0];
    int4* dl = (int4*)&xs[row * XLDA + 256 + d0];
    #pragma unroll
    for (int i = 0; i < 4; ++i) { dh[i] = hi.q[i]; dl[i] = lo.q[i]; }
  }

  const int lane = tid & 63, wave = tid >> 6;
  const int wr = (wave >> 1) * 16;
  const int wc = wave & 1;
  const int l15 = lane & 15, oct = lane >> 4;
  const int scol = tid >> 1, shalf = tid & 1;
  int4 br[4];

  f32x4 accO[4];
  #pragma unroll
  for (int i = 0; i < 4; ++i) accO[i] = (f32x4)0.f;

  for (int nc = 0; nc < 4; ++nc) {
    f32x4 acc1[4];
    #pragma unroll
    for (int i = 0; i < 4; ++i) acc1[i] = (f32x4)0.f;
    // ---- layer 1 chunk
    {
      auto loadB1 = [&](int c) {
        int ko = c * 64, seg = ko >> 8, wi = ko & 255;
        int pb = (seg == 2) ? 256 + wi : wi;
        const int4* p = (const int4*)(B1k + (size_t)(nc * 128 + scol) * 512 + pb + shalf * 32);
        br[0] = p[0]; br[1] = p[1]; br[2] = p[2]; br[3] = p[3];
      };
      loadB1(0);
      for (int c = 0; c < 12; ++c) {
        __syncthreads();
        { int4* d4 = (int4*)&Bst[scol * BLDA + shalf * 32];
          d4[0] = br[0]; d4[1] = br[1]; d4[2] = br[2]; d4[3] = br[3]; }
        __syncthreads();
        if (c + 1 < 12) loadB1(c + 1);
        int ko = c * 64, seg = ko >> 8, wi = ko & 255;
        int pa = (seg == 1) ? 256 + wi : wi;
        #pragma unroll
        for (int s = 0; s < 2; ++s) {
          bf16x8 a = *(const bf16x8*)&xs[(wr + l15) * XLDA + pa + s * 32 + oct * 8];
          #pragma unroll
          for (int cf = 0; cf < 4; ++cf) {
            bf16x8 b = *(const bf16x8*)&Bst[(wc * 64 + cf * 16 + l15) * BLDA + s * 32 + oct * 8];
            acc1[cf] = __builtin_amdgcn_mfma_f32_16x16x32_bf16(a, b, acc1[cf], 0, 0, 0);
          }
        }
      }
    }
    #pragma unroll
    for (int cf = 0; cf < 4; ++cf) {
      int colL = wc * 64 + cf * 16 + l15;
      float bv = bl1[kfn * 512 + nc * 128 + colL];
      #pragma unroll
      for (int j = 0; j < 4; ++j) {
        int row = wr + oct * 4 + j;
        float v = fmaxf(acc1[cf][j] + bv, 0.f);
        unsigned short hh = f2bf(v);
        a1c[row * A1LDA + colL]       = (short)hh;
        a1c[row * A1LDA + 128 + colL] = (short)f2bf(v - bf2f(hh));
      }
    }
    // ---- layer 2 partial: N=128, chunk logical K = 384
    {
      auto loadB2 = [&](int cc) {
        int ko = cc * 64, seg = ko >> 7, wi = ko & 127;
        int pb = (seg == 2) ? 512 + nc * 128 + wi : nc * 128 + wi;
        const int4* p = (const int4*)(B2k + (size_t)scol * 1024 + pb + shalf * 32);
        br[0] = p[0]; br[1] = p[1]; br[2] = p[2]; br[3] = p[3];
      };
      loadB2(0);
      for (int cc = 0; cc < 6; ++cc) {
        __syncthreads();
        { int4* d4 = (int4*)&Bst[scol * BLDA + shalf * 32];
          d4[0] = br[0]; d4[1] = br[1]; d4[2] = br[2]; d4[3] = br[3]; }
        __syncthreads();
        if (cc + 1 < 6) loadB2(cc + 1);
        int ko = cc * 64, seg = ko >> 7, wi = ko & 127;
        int pa = (seg == 1) ? 128 + wi : wi;
        #pragma unroll
        for (int s = 0; s < 2; ++s) {
          bf16x8 a = *(const bf16x8*)&a1c[(wr + l15) * A1LDA + pa + s * 32 + oct * 8];
          #pragma unroll
          for (int cf = 0; cf < 4; ++cf) {
            bf16x8 b = *(const bf16x8*)&Bst[(wc * 64 + cf * 16 + l15) * BLDA + s * 32 + oct * 8];
            accO[cf] = __builtin_amdgcn_mfma_f32_16x16x32_bf16(a, b, accO[cf], 0, 0, 0);
          }
        }
      }
    }
  }
  // epilogue: bias + scatter to out
  #pragma unroll
  for (int cf = 0; cf < 4; ++cf) {
    int col = wc * 64 + cf * 16 + l15;
    float bv = bl2[kfn * 128 + col];
    #pragma unroll
    for (int j = 0; j < 4; ++j) {
      int row = wr + oct * 4 + j;
      int node = nodesS[row];
      if (node >= 0) out[(size_t)node * 128 + col] = accO[cf][j] + bv;
    }
  }
}

// ---------------------------------------------------------------------------
extern "C" void kernel_launch(void* const* d_in, const int* in_sizes, int n_in,
                              void* d_out, int out_size, void* d_ws, size_t ws_size,
                              hipStream_t stream) {
  const int*   leaf_ids  = (const int*)d_in[0];
  const int*   left_idx  = (const int*)d_in[1];
  const int*   right_idx = (const int*)d_in[2];
  const int*   nf_fid    = (const int*)d_in[3];
  const int*   gt_left   = (const int*)d_in[4];
  const int*   gt_right  = (const int*)d_in[5];
  const int*   lf_fid    = (const int*)d_in[6];
  const float* emb       = (const float*)d_in[7];
  const float* W1 = (const float*)d_in[8];
  const float* b1 = (const float*)d_in[9];
  const float* W2 = (const float*)d_in[10];
  const float* b2 = (const float*)d_in[11];
  const float* W3 = (const float*)d_in[12];
  const float* b3 = (const float*)d_in[13];
  const float* Wl1 = (const float*)d_in[14];
  const float* bl1 = (const float*)d_in[15];
  const float* Wl2 = (const float*)d_in[16];
  const float* bl2 = (const float*)d_in[17];
  float* out = (float*)d_out;

  // workspace layout (~20.5 MB; round-2 path needed ~90 MB and fit, so OK)
  const size_t SZ_H    = (size_t)M * D * 4;
  const size_t SZ_B1T  = (size_t)8 * 512 * 512 * 2;
  const size_t SZ_B2T  = (size_t)8 * 256 * 1024 * 2;
  const size_t SZ_B3T  = (size_t)8 * 128 * 512 * 2;
  const size_t SZ_BL1T = (size_t)4 * 512 * 512 * 2;
  const size_t SZ_BL2T = (size_t)4 * 128 * 1024 * 2;

  char* p = (char*)d_ws;
  float* hA   = (float*)p;  p += SZ_H;
  float* hB   = (float*)p;  p += SZ_H;
  short* B1T  = (short*)p;  p += SZ_B1T;
  short* B2T  = (short*)p;  p += SZ_B2T;
  short* B3T  = (short*)p;  p += SZ_B3T;
  short* BL1T = (short*)p;  p += SZ_BL1T;
  short* BL2T = (short*)p;  p += SZ_BL2T;
  int*   orders = (int*)p;

  leaf_gather_kernel<<<(M * D) / 256, 256, 0, stream>>>(leaf_ids, emb, hA);
  bucket32_kernel<<<L + 1, 256, 0, stream>>>(nf_fid, lf_fid, orders);
  prep_kernel<<<9728, 256, 0, stream>>>(W1, W2, W3, Wl1, Wl2,
                                        B1T, B2T, B3T, BL1T, BL2T);

  float* hin = hA;
  float* hout = hB;
  for (int l = 0; l < L; ++l) {
    level_fused<<<PADL / TR, 256, 0, stream>>>(
        hin, hout, orders + l * PADL, nf_fid + l * M,
        left_idx + l * M, right_idx + l * M,
        B1T, b1, B2T, b2, B3T, b3);
    float* t = hin; hin = hout; hout = t;
  }
  logic_fused<<<PADG / TR, 256, 0, stream>>>(
      hin, out, orders + L * PADL, lf_fid, gt_left, gt_right,
      BL1T, bl1, BL2T, bl2);
}

// Round 4
// 515.422 us; speedup vs baseline: 2.7244x; 2.7244x over previous
//
#include <hip/hip_runtime.h>

// Problem constants
constexpr int D  = 128;
constexpr int M  = 8192;
constexpr int L  = 5;
constexpr int K  = 8;
constexpr int KL = 4;
constexpr int G  = 4096;

constexpr int TB   = 64;            // bucket pad granularity
constexpr int PADL = M + K * TB;    // 8704
constexpr int PADG = G + KL * TB;   // 4352

typedef short bf16x8 __attribute__((ext_vector_type(8)));
typedef float f32x4  __attribute__((ext_vector_type(4)));

__device__ __forceinline__ unsigned short f2bf(float x) {
  union { float f; unsigned int u; } c; c.f = x;
  unsigned int u = c.u + 0x7FFF + ((c.u >> 16) & 1);   // RNE
  return (unsigned short)(u >> 16);
}
__device__ __forceinline__ float bf2f(unsigned short h) {
  union { unsigned int u; float f; } c; c.u = ((unsigned int)h) << 16;
  return c.f;
}

// ---------------------------------------------------------------------------
__global__ void leaf_gather_kernel(const int* __restrict__ leaf_ids,
                                   const float* __restrict__ emb,
                                   float* __restrict__ h0) {
  int idx = blockIdx.x * 256 + threadIdx.x;
  int n = idx >> 7, d = idx & 127;
  h0[idx] = emb[(size_t)leaf_ids[n] * D + d];
}

// ---------------------------------------------------------------------------
// Bucket node indices by fid, padded to 64; pad = -1. Valid entries are a
// prefix of each bucket, so every 64-tile AND every 32-tile is fid-uniform.
__global__ void bucket64_kernel(const int* __restrict__ nf_fid,
                                const int* __restrict__ lf_fid,
                                int* __restrict__ orders) {
  int b = blockIdx.x;
  const int* fid; int N, Kf, cap; int* out;
  if (b < L) { fid = nf_fid + b * M; N = M; Kf = K;  cap = PADL; out = orders + b * PADL; }
  else       { fid = lf_fid;         N = G; Kf = KL; cap = PADG; out = orders + L * PADL; }
  __shared__ int cnt[8];
  __shared__ int cur[8];
  int tid = threadIdx.x;
  if (tid < Kf) cnt[tid] = 0;
  __syncthreads();
  for (int i = tid; i < N; i += 256) atomicAdd(&cnt[fid[i]], 1);
  __syncthreads();
  if (tid == 0) {
    int off = 0;
    for (int k = 0; k < Kf; ++k) { cur[k] = off; off += ((cnt[k] + TB - 1) / TB) * TB; }
  }
  __syncthreads();
  for (int i = tid; i < cap; i += 256) out[i] = -1;
  __syncthreads();
  for (int i = tid; i < N; i += 256) {
    int kk = fid[i];
    int pos = atomicAdd(&cur[kk], 1);
    out[pos] = i;
  }
}

// ---------------------------------------------------------------------------
// Weight prep: W[k][KD][F] fp32 -> BT[k][F][2*KD] bf16 as [hi(KD) | lo(KD)].
__global__ void prep_kernel(const float* __restrict__ W1, const float* __restrict__ W2,
                            const float* __restrict__ W3, const float* __restrict__ Wl1,
                            const float* __restrict__ Wl2,
                            short* __restrict__ B1T, short* __restrict__ B2T,
                            short* __restrict__ B3T, short* __restrict__ BL1T,
                            short* __restrict__ BL2T) {
  int b = blockIdx.x;
  const float* W; short* BT; int KD, F;
  if      (b < 4096) { W = W1;  BT = B1T;  KD = 256; F = 512; }
  else if (b < 6144) { W = W2;  BT = B2T;  KD = 512; F = 256; b -= 4096; }
  else if (b < 7168) { W = W3;  BT = B3T;  KD = 256; F = 128; b -= 6144; }
  else if (b < 9216) { W = Wl1; BT = BL1T; KD = 256; F = 512; b -= 7168; }
  else               { W = Wl2; BT = BL2T; KD = 512; F = 128; b -= 9216; }
  int k = b / F, f = b % F;
  for (int d = threadIdx.x; d < KD; d += 256) {
    float w = W[((size_t)k * KD + d) * F + f];
    unsigned short hi = f2bf(w);
    unsigned short lo = f2bf(w - bf2f(hi));
    BT[((size_t)k * F + f) * (2 * KD) + d]      = (short)hi;
    BT[((size_t)k * F + f) * (2 * KD) + KD + d] = (short)lo;
  }
}

// ---------------------------------------------------------------------------
// Grouped GEMM, split-bf16 (logical K' = 3*KH over phys layout [hi|lo]):
//   A' segs {0,1,2} -> phys {hi(0), lo(KH), hi(0)}
//   B' segs {0,1,2} -> phys {hi(0), hi(0), lo(KH)}
// Block: 256 thr, TROWS x 128 tile, waves 2x2 (wave tile TROWS/2 x 64).
// Depth-2 register prefetch (two sets), single LDS buffer, 2 barriers/chunk.
// EPI=0: relu(acc+bias) -> split hi/lo bf16 to Aout, coalesced via LDS.
// EPI=1: acc+bias -> fp32 scatter to outp[node], coalesced via LDS.
template<int KH, int NN, int EPI, int FUSED, int TROWS>
__global__ __launch_bounds__(256) void mfma_gemm(
    const short* __restrict__ A, const float* __restrict__ hsrc,
    const int* __restrict__ gl, const int* __restrict__ gr,
    const short* __restrict__ BT, const float* __restrict__ bias,
    short* __restrict__ Aout, float* __restrict__ outp,
    const int* __restrict__ order, const int* __restrict__ fid) {
  static_assert(FUSED == 0 || TROWS == 64, "fused gather assumes 64-row tiles");
  constexpr int BK  = 64;
  constexpr int NCH = 3 * KH / BK;        // 12 or 24 (even)
  constexpr int LDA = BK + 8;             // 72 shorts -> 2-way bank alias (free)
  constexpr int RF  = TROWS / 32;         // row frags per wave: 2 or 1
  constexpr int TPR = 256 / TROWS;        // A-staging threads per row: 4 or 8
  __shared__ __align__(16) short As[TROWS * LDA];
  __shared__ __align__(16) short Bs[128 * LDA];
  __shared__ int nodesS[TROWS], liS[TROWS], riS[TROWS];

  const int tid = threadIdx.x;
  const int row0 = blockIdx.x * TROWS;
  const int ct = blockIdx.y;

  if (tid < TROWS) {
    int node = order[row0 + tid];
    nodesS[tid] = node;
    if (FUSED) {
      liS[tid] = node >= 0 ? gl[node] : 0;
      riS[tid] = node >= 0 ? gr[node] : 0;
    }
  }
  __syncthreads();
  if (nodesS[0] < 0) return;              // fully-padded tile
  const int kfn = fid[nodesS[0]];
  const short* __restrict__ Bk = BT + (size_t)kfn * NN * (2 * KH);

  const int lane = tid & 63, wave = tid >> 6;
  const int wr = (wave >> 1) * (TROWS / 2);
  const int wc = wave & 1;
  const int l15 = lane & 15, oct = lane >> 4;

  const int ar = tid / TPR;                    // A staging row
  const int ag = (tid % TPR) * (BK / TPR);     // A short offset (16 or 8)
  const int bn = tid >> 1;                     // B staging col-row
  const int bg = (tid & 1) * 32;               // B short offset

  f32x4 acc[RF][4];
  #pragma unroll
  for (int i = 0; i < RF; ++i)
    #pragma unroll
    for (int j = 0; j < 4; ++j) acc[i][j] = (f32x4)0.f;

  // two prefetch register sets
  int4 A00, A01, A10, A11;
  float4 F00, F01, F02, F03, F10, F11, F12, F13;
  int4 B00, B01, B02, B03, B10, B11, B12, B13;

  auto loadB_to = [&](int c, int4& r0, int4& r1, int4& r2, int4& r3) {
    int ko = c * BK, seg = ko / KH, wi = ko % KH;
    int pb = (seg == 2) ? KH + wi : wi;
    const int4* p = (const int4*)(Bk + (size_t)(ct * 128 + bn) * (2 * KH) + pb + bg);
    r0 = p[0]; r1 = p[1]; r2 = p[2]; r3 = p[3];
  };
  auto loadA_to = [&](int c, int4& r0, int4& r1,
                      float4& f0, float4& f1, float4& f2, float4& f3) {
    int ko = c * BK, seg = ko / KH, wi = ko % KH;
    if (FUSED) {
      int dl = wi + ag;               // 16 dims per thread
      if (nodesS[ar] >= 0) {
        const float* src = (dl < 128) ? (hsrc + (size_t)liS[ar] * 128 + dl)
                                      : (hsrc + (size_t)riS[ar] * 128 + (dl - 128));
        const float4* p = (const float4*)src;
        f0 = p[0]; f1 = p[1]; f2 = p[2]; f3 = p[3];
      } else {
        f0 = f1 = f2 = f3 = make_float4(0.f, 0.f, 0.f, 0.f);
      }
    } else {
      int pa = (seg == 1) ? KH + wi : wi;
      const int4* p = (const int4*)(A + (size_t)(row0 + ar) * (2 * KH) + pa + ag);
      r0 = p[0];
      if (TPR == 4) r1 = p[1];
    }
  };
  auto storeLDS_from = [&](int c, int4& r0, int4& r1,
                           float4& f0, float4& f1, float4& f2, float4& f3,
                           int4& b0, int4& b1, int4& b2, int4& b3) {
    if (FUSED) {
      int seg = (c * BK) / KH;
      float v[16];
      ((float4*)v)[0] = f0; ((float4*)v)[1] = f1;
      ((float4*)v)[2] = f2; ((float4*)v)[3] = f3;
      union { unsigned short u[16]; int4 q[2]; } o;
      if (seg != 1) {
        #pragma unroll
        for (int i = 0; i < 16; ++i) o.u[i] = f2bf(v[i]);
      } else {
        #pragma unroll
        for (int i = 0; i < 16; ++i) {
          unsigned short hh = f2bf(v[i]);
          o.u[i] = f2bf(v[i] - bf2f(hh));
        }
      }
      int4* d4 = (int4*)&As[ar * LDA + ag];
      d4[0] = o.q[0]; d4[1] = o.q[1];
    } else {
      int4* d4 = (int4*)&As[ar * LDA + ag];
      d4[0] = r0;
      if (TPR == 4) d4[1] = r1;
    }
    int4* db = (int4*)&Bs[bn * LDA + bg];
    db[0] = b0; db[1] = b1; db[2] = b2; db[3] = b3;
  };
  auto compute = [&]() {
    #pragma unroll
    for (int s = 0; s < 2; ++s) {
      const int ko = s * 32 + oct * 8;
      bf16x8 afr[RF];
      #pragma unroll
      for (int rf = 0; rf < RF; ++rf)
        afr[rf] = *(const bf16x8*)&As[(wr + rf * 16 + l15) * LDA + ko];
      #pragma unroll
      for (int cf = 0; cf < 4; ++cf) {
        bf16x8 b = *(const bf16x8*)&Bs[(wc * 64 + cf * 16 + l15) * LDA + ko];
        #pragma unroll
        for (int rf = 0; rf < RF; ++rf)
          acc[rf][cf] = __builtin_amdgcn_mfma_f32_16x16x32_bf16(afr[rf], b, acc[rf][cf], 0, 0, 0);
      }
    }
  };

  loadA_to(0, A00, A01, F00, F01, F02, F03);
  loadB_to(0, B00, B01, B02, B03);
  loadA_to(1, A10, A11, F10, F11, F12, F13);
  loadB_to(1, B10, B11, B12, B13);
  for (int c = 0; c < NCH; c += 2) {
    __syncthreads();
    storeLDS_from(c, A00, A01, F00, F01, F02, F03, B00, B01, B02, B03);
    __syncthreads();
    if (c + 2 < NCH) {
      loadA_to(c + 2, A00, A01, F00, F01, F02, F03);
      loadB_to(c + 2, B00, B01, B02, B03);
    }
    compute();
    __syncthreads();
    storeLDS_from(c + 1, A10, A11, F10, F11, F12, F13, B10, B11, B12, B13);
    __syncthreads();
    if (c + 3 < NCH) {
      loadA_to(c + 3, A10, A11, F10, F11, F12, F13);
      loadB_to(c + 3, B10, B11, B12, B13);
    }
    compute();
  }

  // ---- Epilogue (coalesced via LDS; Bs is free after the final compute)
  if (EPI == 0) {
    short* Ls = (short*)Bs;                  // TROWS*128 shorts (<= 16 KB)
    #pragma unroll
    for (int part = 0; part < 2; ++part) {
      __syncthreads();
      #pragma unroll
      for (int rf = 0; rf < RF; ++rf)
        #pragma unroll
        for (int cf = 0; cf < 4; ++cf) {
          int colL = wc * 64 + cf * 16 + l15;
          float bv = bias[kfn * NN + ct * 128 + colL];
          #pragma unroll
          for (int j = 0; j < 4; ++j) {
            int row = wr + rf * 16 + oct * 4 + j;
            float v = fmaxf(acc[rf][cf][j] + bv, 0.f);
            unsigned short hh = f2bf(v);
            unsigned short val = (part == 0) ? hh : f2bf(v - bf2f(hh));
            Ls[row * 128 + colL] = (short)val;
          }
        }
      __syncthreads();
      constexpr int SPT = TROWS / 2;         // shorts per thread (32 or 16)
      constexpr int TPW = 128 / SPT;         // threads per row (4 or 8)
      int row = tid / TPW, sg = (tid % TPW) * SPT;
      const int4* src = (const int4*)&Ls[row * 128 + sg];
      int4* dst = (int4*)&Aout[(size_t)(row0 + row) * (2 * NN) + part * NN + ct * 128 + sg];
      #pragma unroll
      for (int q = 0; q < SPT / 8; ++q) dst[q] = src[q];
    }
  } else {
    float* Lf = (float*)Bs;                  // TROWS*64 floats (<= 16 KB)
    #pragma unroll
    for (int h = 0; h < 2; ++h) {
      __syncthreads();
      if (wc == h) {
        #pragma unroll
        for (int rf = 0; rf < RF; ++rf)
          #pragma unroll
          for (int cf = 0; cf < 4; ++cf) {
            int colL = cf * 16 + l15;
            float bv = bias[kfn * 128 + h * 64 + colL];
            #pragma unroll
            for (int j = 0; j < 4; ++j) {
              int row = wr + rf * 16 + oct * 4 + j;
              Lf[row * 64 + colL] = acc[rf][cf][j] + bv;
            }
          }
      }
      __syncthreads();
      constexpr int FPT = TROWS / 4;         // floats per thread (16 or 8)
      constexpr int TPW = 64 / FPT;          // threads per row (4 or 8)
      int row = tid / TPW, off = (tid % TPW) * FPT;
      int node = nodesS[row];
      if (node >= 0) {
        const float4* src = (const float4*)&Lf[row * 64 + off];
        float4* dst = (float4*)&outp[(size_t)node * 128 + h * 64 + off];
        #pragma unroll
        for (int q = 0; q < FPT / 4; ++q) dst[q] = src[q];
      }
    }
  }
}

// ---------------------------------------------------------------------------
extern "C" void kernel_launch(void* const* d_in, const int* in_sizes, int n_in,
                              void* d_out, int out_size, void* d_ws, size_t ws_size,
                              hipStream_t stream) {
  const int*   leaf_ids  = (const int*)d_in[0];
  const int*   left_idx  = (const int*)d_in[1];
  const int*   right_idx = (const int*)d_in[2];
  const int*   nf_fid    = (const int*)d_in[3];
  const int*   gt_left   = (const int*)d_in[4];
  const int*   gt_right  = (const int*)d_in[5];
  const int*   lf_fid    = (const int*)d_in[6];
  const float* emb       = (const float*)d_in[7];
  const float* W1 = (const float*)d_in[8];
  const float* b1 = (const float*)d_in[9];
  const float* W2 = (const float*)d_in[10];
  const float* b2 = (const float*)d_in[11];
  const float* W3 = (const float*)d_in[12];
  const float* b3 = (const float*)d_in[13];
  const float* Wl1 = (const float*)d_in[14];
  const float* bl1 = (const float*)d_in[15];
  const float* Wl2 = (const float*)d_in[16];
  const float* bl2 = (const float*)d_in[17];
  float* out = (float*)d_out;

  // workspace layout (~54 MB; round-2's 90 MB fit, so this fits)
  const size_t SZ_H    = (size_t)M * D * 4;
  const size_t SZ_A1   = (size_t)PADL * 1024 * 2;
  const size_t SZ_A2   = (size_t)PADL * 512 * 2;
  const size_t SZ_B1T  = (size_t)8 * 512 * 512 * 2;
  const size_t SZ_B2T  = (size_t)8 * 256 * 1024 * 2;
  const size_t SZ_B3T  = (size_t)8 * 128 * 512 * 2;
  const size_t SZ_BL1T = (size_t)4 * 512 * 512 * 2;
  const size_t SZ_BL2T = (size_t)4 * 128 * 1024 * 2;

  char* p = (char*)d_ws;
  float* hA   = (float*)p;  p += SZ_H;
  float* hB   = (float*)p;  p += SZ_H;
  short* a1s  = (short*)p;  p += SZ_A1;
  short* a2s  = (short*)p;  p += SZ_A2;
  short* B1T  = (short*)p;  p += SZ_B1T;
  short* B2T  = (short*)p;  p += SZ_B2T;
  short* B3T  = (short*)p;  p += SZ_B3T;
  short* BL1T = (short*)p;  p += SZ_BL1T;
  short* BL2T = (short*)p;  p += SZ_BL2T;
  int*   orders = (int*)p;

  leaf_gather_kernel<<<(M * D) / 256, 256, 0, stream>>>(leaf_ids, emb, hA);
  bucket64_kernel<<<L + 1, 256, 0, stream>>>(nf_fid, lf_fid, orders);
  prep_kernel<<<9728, 256, 0, stream>>>(W1, W2, W3, Wl1, Wl2,
                                        B1T, B2T, B3T, BL1T, BL2T);

  float* hin = hA;
  float* hout = hB;
  for (int l = 0; l < L; ++l) {
    const int* ord = orders + l * PADL;
    const int* fidl = nf_fid + l * M;
    // GEMM1: fused gather, K'=3*256, N=512, relu+split  (136x4 = 544 blocks)
    mfma_gemm<256, 512, 0, 1, 64><<<dim3(PADL / 64, 4), 256, 0, stream>>>(
        nullptr, hin, left_idx + l * M, right_idx + l * M,
        B1T, b1, a1s, nullptr, ord, fidl);
    // GEMM2: K'=3*512, N=256, relu+split                (136x2 = 272 blocks)
    mfma_gemm<512, 256, 0, 0, 64><<<dim3(PADL / 64, 2), 256, 0, stream>>>(
        a1s, nullptr, nullptr, nullptr,
        B2T, b2, a2s, nullptr, ord, fidl);
    // GEMM3: K'=3*256, N=128, bias+scatter fp32         (272 blocks, 32-row)
    mfma_gemm<256, 128, 1, 0, 32><<<dim3(PADL / 32, 1), 256, 0, stream>>>(
        a2s, nullptr, nullptr, nullptr,
        B3T, b3, nullptr, hout, ord, fidl);
    float* t = hin; hin = hout; hout = t;
  }
  const int* ordG = orders + L * PADL;
  // Logic GEMM1: fused gather from final h              (68x4 = 272 blocks)
  mfma_gemm<256, 512, 0, 1, 64><<<dim3(PADG / 64, 4), 256, 0, stream>>>(
      nullptr, hin, gt_left, gt_right,
      BL1T, bl1, a1s, nullptr, ordG, lf_fid);
  // Logic GEMM2: K'=3*512, N=128, bias+scatter to d_out (136 blocks, 32-row)
  mfma_gemm<512, 128, 1, 0, 32><<<dim3(PADG / 32, 1), 256, 0, stream>>>(
      a1s, nullptr, nullptr, nullptr,
      BL2T, bl2, nullptr, out, ordG, lf_fid);
}